// Round 12
// baseline (288.968 us; speedup 1.0000x reference)
//
#include <hip/hip_runtime.h>
#include <math.h>

#define NR 36
#define NW 32
#define DD 1024
#define EPSF 1e-8f

typedef _Float16 f16x8 __attribute__((ext_vector_type(8)));
typedef float f32x16 __attribute__((ext_vector_type(16)));
#define MFMA32(a, b, c) __builtin_amdgcn_mfma_f32_32x32x16_f16((a), (b), (c), 0, 0, 0)
#define GLD16(srcp, dstp)                                                              \
  __builtin_amdgcn_global_load_lds((const __attribute__((address_space(1))) void*)(srcp), \
                                   (__attribute__((address_space(3))) void*)(dstp), 16, 0, 0)

__device__ __forceinline__ float leakyf(float x) { return x > 0.f ? x : 0.1f * x; }

// ============ prep v3: hi-plane only (A and B); XOR-swizzled gram LDS; T14 async-stage =====
__global__ __launch_bounds__(256) void prep_kernel(
    const float* __restrict__ img, const float* __restrict__ cap,
    float* __restrict__ Gimg, float* __restrict__ Gcap,
    float* __restrict__ imgn, float* __restrict__ capn,
    _Float16* __restrict__ Ahf, _Float16* __restrict__ Alf,
    _Float16* __restrict__ Bhf, _Float16* __restrict__ Blf) {
  __shared__ float sA[2][NR][64];
  const int t = threadIdx.x;
  if (blockIdx.x < 128) {
    const int i = blockIdx.x;
    const float* A = img + (size_t)i * NR * DD;
    int ti = 0, tj = 0;
    const bool active = t < 171;  // 18*19/2 upper-tri 2x2 tiles
    if (active) {
      int rem = t, rl = 18;
      while (rem >= rl) { rem -= rl; ++ti; --rl; }
      tj = ti + rem;
    }
    const int a0 = 2 * ti, a1 = 2 * ti + 1, b0 = 2 * tj, b1 = 2 * tj + 1;
    const int sza = ti & 7, szb = tj & 7;
    const int kq8_1 = t / NR, r1 = t - kq8_1 * NR;
    const bool has2 = t < 32;
    const int s2 = t + 256;
    const int kq8_2 = s2 / NR, r2 = s2 - kq8_2 * NR;
    float4 p0a, p1a, p0b, p1b;
    float g00 = 0.f, g01 = 0.f, g10 = 0.f, g11 = 0.f;

    auto loadRegs = [&](int idx) {
      const int k0 = idx * 64;
      p0a = *(const float4*)(A + r1 * DD + k0 + kq8_1 * 8);
      p1a = *(const float4*)(A + r1 * DD + k0 + kq8_1 * 8 + 4);
      if (has2) {
        p0b = *(const float4*)(A + r2 * DD + k0 + kq8_2 * 8);
        p1b = *(const float4*)(A + r2 * DD + k0 + kq8_2 * 8 + 4);
      }
    };
    auto cw = [&](int idx, int cur) {
      const int k0 = idx * 64;
      {
        const float a[8] = {p0a.x, p0a.y, p0a.z, p0a.w, p1a.x, p1a.y, p1a.z, p1a.w};
        f16x8 hv;
#pragma unroll
        for (int j = 0; j < 8; ++j) hv[j] = (_Float16)a[j];
        const int m = i * NR + r1, mt = m >> 5, ml = m & 31;
        const int kk = k0 + kq8_1 * 8;
        const size_t fo = (((size_t)mt * 128 + (kk >> 3)) * 32 + ml) * 8;
        *(f16x8*)(Ahf + fo) = hv;
        const int sw = (r1 >> 1) & 7;
        *(float4*)&sA[cur][r1][((2 * kq8_1) ^ sw) * 4] = p0a;
        *(float4*)&sA[cur][r1][((2 * kq8_1 + 1) ^ sw) * 4] = p1a;
      }
      if (has2) {
        const float a[8] = {p0b.x, p0b.y, p0b.z, p0b.w, p1b.x, p1b.y, p1b.z, p1b.w};
        f16x8 hv;
#pragma unroll
        for (int j = 0; j < 8; ++j) hv[j] = (_Float16)a[j];
        const int m = i * NR + r2, mt = m >> 5, ml = m & 31;
        const int kk = k0 + kq8_2 * 8;
        const size_t fo = (((size_t)mt * 128 + (kk >> 3)) * 32 + ml) * 8;
        *(f16x8*)(Ahf + fo) = hv;
        const int sw = (r2 >> 1) & 7;
        *(float4*)&sA[cur][r2][((2 * kq8_2) ^ sw) * 4] = p0b;
        *(float4*)&sA[cur][r2][((2 * kq8_2 + 1) ^ sw) * 4] = p1b;
      }
    };

    loadRegs(0);
    for (int idx = 0; idx < 16; ++idx) {
      const int cur = idx & 1;
      cw(idx, cur);
      if (idx < 15) loadRegs(idx + 1);
      __syncthreads();
      if (active) {
#pragma unroll
        for (int k = 0; k < 16; ++k) {
          const float4 va0 = *(const float4*)&sA[cur][a0][(k ^ sza) * 4];
          const float4 va1 = *(const float4*)&sA[cur][a1][(k ^ sza) * 4];
          const float4 vb0 = *(const float4*)&sA[cur][b0][(k ^ szb) * 4];
          const float4 vb1 = *(const float4*)&sA[cur][b1][(k ^ szb) * 4];
          g00 = fmaf(va0.x, vb0.x, g00); g00 = fmaf(va0.y, vb0.y, g00);
          g00 = fmaf(va0.z, vb0.z, g00); g00 = fmaf(va0.w, vb0.w, g00);
          g01 = fmaf(va0.x, vb1.x, g01); g01 = fmaf(va0.y, vb1.y, g01);
          g01 = fmaf(va0.z, vb1.z, g01); g01 = fmaf(va0.w, vb1.w, g01);
          g10 = fmaf(va1.x, vb0.x, g10); g10 = fmaf(va1.y, vb0.y, g10);
          g10 = fmaf(va1.z, vb0.z, g10); g10 = fmaf(va1.w, vb0.w, g10);
          g11 = fmaf(va1.x, vb1.x, g11); g11 = fmaf(va1.y, vb1.y, g11);
          g11 = fmaf(va1.z, vb1.z, g11); g11 = fmaf(va1.w, vb1.w, g11);
        }
      }
    }
    if (active) {
      float* Gi = Gimg + (size_t)i * NR * NR;
      Gi[a0 * NR + b0] = g00; Gi[b0 * NR + a0] = g00;
      Gi[a0 * NR + b1] = g01; Gi[b1 * NR + a0] = g01;
      Gi[a1 * NR + b0] = g10; Gi[b0 * NR + a1] = g10;
      Gi[a1 * NR + b1] = g11; Gi[b1 * NR + a1] = g11;
      if (ti == tj) {
        imgn[i * NR + a0] = fmaxf(sqrtf(g00), EPSF);
        imgn[i * NR + a1] = fmaxf(sqrtf(g11), EPSF);
      }
    }
  } else {
    const int cb = blockIdx.x - 128;
    const float* A = cap + (size_t)cb * NW * DD;
    int ti = 0, tj = 0;
    const bool active = t < 136;  // 16*17/2
    if (active) {
      int rem = t, rl = 16;
      while (rem >= rl) { rem -= rl; ++ti; --rl; }
      tj = ti + rem;
    }
    const int a0 = 2 * ti, a1 = 2 * ti + 1, b0 = 2 * tj, b1 = 2 * tj + 1;
    const int sza = ti & 7, szb = tj & 7;
    const int kq8_1 = t >> 5, r1 = t & 31;
    float4 p0a, p1a;
    float g00 = 0.f, g01 = 0.f, g10 = 0.f, g11 = 0.f;

    auto loadRegs = [&](int idx) {
      const int k0 = idx * 64;
      p0a = *(const float4*)(A + r1 * DD + k0 + kq8_1 * 8);
      p1a = *(const float4*)(A + r1 * DD + k0 + kq8_1 * 8 + 4);
    };
    auto cw = [&](int idx, int cur) {
      const int k0 = idx * 64;
      const float a[8] = {p0a.x, p0a.y, p0a.z, p0a.w, p1a.x, p1a.y, p1a.z, p1a.w};
      f16x8 hv;
#pragma unroll
      for (int j = 0; j < 8; ++j) hv[j] = (_Float16)a[j];
      const int kk = k0 + kq8_1 * 8;
      const size_t fo = (((size_t)cb * 128 + (kk >> 3)) * 32 + r1) * 8;
      *(f16x8*)(Bhf + fo) = hv;  // hi plane only
      const int sw = (r1 >> 1) & 7;
      *(float4*)&sA[cur][r1][((2 * kq8_1) ^ sw) * 4] = p0a;
      *(float4*)&sA[cur][r1][((2 * kq8_1 + 1) ^ sw) * 4] = p1a;
    };

    loadRegs(0);
    for (int idx = 0; idx < 16; ++idx) {
      const int cur = idx & 1;
      cw(idx, cur);
      if (idx < 15) loadRegs(idx + 1);
      __syncthreads();
      if (active) {
#pragma unroll
        for (int k = 0; k < 16; ++k) {
          const float4 va0 = *(const float4*)&sA[cur][a0][(k ^ sza) * 4];
          const float4 va1 = *(const float4*)&sA[cur][a1][(k ^ sza) * 4];
          const float4 vb0 = *(const float4*)&sA[cur][b0][(k ^ szb) * 4];
          const float4 vb1 = *(const float4*)&sA[cur][b1][(k ^ szb) * 4];
          g00 = fmaf(va0.x, vb0.x, g00); g00 = fmaf(va0.y, vb0.y, g00);
          g00 = fmaf(va0.z, vb0.z, g00); g00 = fmaf(va0.w, vb0.w, g00);
          g01 = fmaf(va0.x, vb1.x, g01); g01 = fmaf(va0.y, vb1.y, g01);
          g01 = fmaf(va0.z, vb1.z, g01); g01 = fmaf(va0.w, vb1.w, g01);
          g10 = fmaf(va1.x, vb0.x, g10); g10 = fmaf(va1.y, vb0.y, g10);
          g10 = fmaf(va1.z, vb0.z, g10); g10 = fmaf(va1.w, vb0.w, g10);
          g11 = fmaf(va1.x, vb1.x, g11); g11 = fmaf(va1.y, vb1.y, g11);
          g11 = fmaf(va1.z, vb1.z, g11); g11 = fmaf(va1.w, vb1.w, g11);
        }
      }
    }
    if (active) {
      float* Gc = Gcap + (size_t)cb * NW * NW;
      Gc[a0 * NW + b0] = g00; Gc[b0 * NW + a0] = g00;
      Gc[a0 * NW + b1] = g01; Gc[b1 * NW + a0] = g01;
      Gc[a1 * NW + b0] = g10; Gc[b0 * NW + a1] = g10;
      Gc[a1 * NW + b1] = g11; Gc[b1 * NW + a1] = g11;
      if (ti == tj) {
        capn[cb * NW + a0] = fmaxf(sqrtf(g00), EPSF);
        capn[cb * NW + a1] = fmaxf(sqrtf(g11), EPSF);
      }
    }
  }
}

// ============ MFMA GEMM v6: BK=64 phases — 1 barrier per 16 MFMA (kept from r11, ~60us) =====
__device__ __forceinline__ void gemm_loadA(const _Float16* __restrict__ Ahf, int Mt0, int kt,
                                           int kb, int lm, f16x8 ar[2][2]) {
#pragma unroll
  for (int mt = 0; mt < 2; ++mt)
#pragma unroll
    for (int ks = 0; ks < 2; ++ks) {
      const size_t o = (((size_t)(Mt0 + mt) * 128) + kt * 4 + ks * 2 + kb) * 256 + lm * 8;
      ar[mt][ks] = *(const f16x8*)(Ahf + o);
    }
}

__global__ __launch_bounds__(256) void mfma_gemm_kernel(
    const _Float16* __restrict__ Ahf, const _Float16* __restrict__ Alf,
    const _Float16* __restrict__ Bhf, const _Float16* __restrict__ Blf, float* __restrict__ C) {
  __shared__ _Float16 sB[2][8192];  // 2 bufs x (2 kt x 8KB): [kh*4096 + (nb*4+kq)*256 + lm*8]
  const int bid0 = blockIdx.x;
  const int bid = (bid0 & 7) * 144 + (bid0 >> 3);  // T1 xb-chunked XCD swizzle (1152=8*144)
  const int yb = bid & 31, xb = bid >> 5;
  const int n0b = yb * 4;
  const int tid = threadIdx.x;
  const int wv = tid >> 6, lane = tid & 63;
  const int lm = lane & 31, kb = lane >> 5;
  const int Mt0 = xb * 4 + (wv >> 1) * 2;
  const int nb0 = (wv & 1) * 2;
  (void)Alf; (void)Blf;

  auto stageB2 = [&](int p, int buf) {  // stage kts 2p, 2p+1
#pragma unroll
    for (int u = 0; u < 4; ++u) {
      const int kt = 2 * p + (u >> 1);
      const int cpb = wv * 4 + (u & 1) * 2;
      const int cp = cpb + kb;
      const int nb = cp >> 2, kq = cp & 3;
      const _Float16* src = Bhf + (((size_t)(n0b + nb) * 128 + kt * 4 + kq) * 32 + lm) * 8;
      GLD16(src, &sB[buf][(u >> 1) * 4096 + cpb * 256]);
    }
  };

  f32x16 acc[2][2];
#pragma unroll
  for (int a = 0; a < 2; ++a)
#pragma unroll
    for (int b = 0; b < 2; ++b) acc[a][b] = {};
  f16x8 arE[2][2][2], arO[2][2][2];  // [kh][mt][ks]

  auto loadA2 = [&](int p, f16x8 ar[2][2][2]) {
#pragma unroll
    for (int kh = 0; kh < 2; ++kh) gemm_loadA(Ahf, Mt0, 2 * p + kh, kb, lm, ar[kh]);
  };
  auto computeHalf = [&](const _Float16* sb, const f16x8 ar[2][2]) {
#pragma unroll
    for (int ks = 0; ks < 2; ++ks)
#pragma unroll
      for (int ntl = 0; ntl < 2; ++ntl) {
        const int nt = nb0 + ntl;
        const int co = (nt * 4 + ks * 2 + kb) * 256 + lm * 8;
        const f16x8 bh = *(const f16x8*)&sb[co];
        acc[0][ntl] = MFMA32(ar[0][ks], bh, acc[0][ntl]);
        acc[1][ntl] = MFMA32(ar[1][ks], bh, acc[1][ntl]);
      }
  };
  auto computeP = [&](const _Float16* sb, const f16x8 ar[2][2][2]) {
    computeHalf(sb, ar[0]);
    computeHalf(sb + 4096, ar[1]);
  };

  stageB2(0, 0);
  loadA2(0, arE);
  for (int pp = 0; pp < 8; ++pp) {
    const int p = 2 * pp;
    __syncthreads();  // stage(p) + A(p) landed
    stageB2(p + 1, 1);
    loadA2(p + 1, arO);
    computeP(sB[0], arE);
    __syncthreads();
    if (p + 2 < 16) {
      stageB2(p + 2, 0);
      loadA2(p + 2, arE);
    }
    computeP(sB[1], arO);
  }
  // epilogue: C/D layout col=lane&31, row=(q&3)+8*(q>>2)+4*kb ; C[((il*128+c)*36+r)*32+w]
#pragma unroll
  for (int mt = 0; mt < 2; ++mt)
#pragma unroll
    for (int ntl = 0; ntl < 2; ++ntl) {
      const int cc = n0b + nb0 + ntl;
      const f32x16 a = acc[mt][ntl];
#pragma unroll
      for (int q = 0; q < 16; ++q) {
        const int row32 = (q & 3) + 8 * (q >> 2) + 4 * kb;
        const int m = (Mt0 + mt) * 32 + row32;
        const int il = m / NR, r = m - il * NR;
        C[((size_t)il * 128 + cc) * (NR * NW) + r * NW + lm] = a[q];
      }
    }
}

// ============ fused v10 = r10's v8 body + bare launch_bounds(192) (kill spills only) ======
// r11 lesson: scalar stride-37 + 2-way trees fixed conflicts/spills but quadrupled LDS
// issues and halved ILP (94.5 -> 119us). v10: v8's float4/4-way body; only the VGPR cap
// changes (r11 proved bare bounds -> 84 regs, no scratch).
#define GCP 1040
__global__ __launch_bounds__(192) void fused_attn_kernel(
    const float* __restrict__ C, const float* __restrict__ Gimg, const float* __restrict__ Gcap,
    const float* __restrict__ imgn, const float* __restrict__ capn, float* __restrict__ out) {
  const int i = blockIdx.x;
  const int cg = blockIdx.y;  // 0..63, 2 caps per block
  const int tid = threadIdx.x;
  const int wv = tid >> 6, lane = tid & 63;
  __shared__ float sS[2][NR * 36];   // scores, row stride 36
  __shared__ float sGi[NR * NR];     // image gram 36x36 (broadcast reads)
  __shared__ float sGc[2 * GCP];     // caption grams 32x32, padded stride 1040
  __shared__ float sInvR[2][NR];
  __shared__ float sInvC[2][NW];
  __shared__ float sVal[72];
  __shared__ float red[2];
  if (tid < 2) red[tid] = 0.f;
  // ---- stage scores + grams ----
  const float* Cp = C + ((size_t)i * 128 + cg * 2) * (NR * NW);
  for (int t = tid; t < 2 * 288; t += 192) {
    const int cap = t / 288, rem = t - cap * 288;
    const int r = rem >> 3, wq = rem & 7;
    const float4 v = *(const float4*)(Cp + cap * (NR * NW) + r * NW + wq * 4);
    *(float4*)&sS[cap][r * 36 + wq * 4] = v;
  }
  const float* Gi = Gimg + (size_t)i * (NR * NR);
  for (int t = tid; t < 324; t += 192) *(float4*)&sGi[t * 4] = *(const float4*)(Gi + t * 4);
  const float* Gc0 = Gcap + (size_t)(cg * 2) * (NW * NW);
  for (int t = tid; t < 512; t += 192) {
    const int cap = t >> 8, q = t & 255;
    *(float4*)&sGc[cap * GCP + q * 4] = *(const float4*)(Gc0 + cap * (NW * NW) + q * 4);
  }
  __syncthreads();
  // ---- norm phase: col-norms (tid<64: 2 caps x 32w) + row-norms (tid 64..135: 2x36) ----
  if (tid < 64) {
    const int cap = tid >> 5, w = tid & 31;
    float c0 = 0.f, c1 = 0.f, c2 = 0.f, c3 = 0.f;
#pragma unroll
    for (int j = 0; j < NR; j += 4) {
      const float l0 = leakyf(sS[cap][(j + 0) * 36 + w]);
      const float l1 = leakyf(sS[cap][(j + 1) * 36 + w]);
      const float l2 = leakyf(sS[cap][(j + 2) * 36 + w]);
      const float l3 = leakyf(sS[cap][(j + 3) * 36 + w]);
      c0 = fmaf(l0, l0, c0); c1 = fmaf(l1, l1, c1);
      c2 = fmaf(l2, l2, c2); c3 = fmaf(l3, l3, c3);
    }
    sInvC[cap][w] = 20.f / (sqrtf((c0 + c1) + (c2 + c3)) + EPSF);
  } else if (tid < 136) {
    const int u = tid - 64;
    const int cap = u / NR, r = u - cap * NR;
    float r0 = 0.f, r1 = 0.f, r2 = 0.f, r3 = 0.f;
#pragma unroll
    for (int k = 0; k < 8; ++k) {
      const float4 v = *(const float4*)&sS[cap][r * 36 + k * 4];
      float l;
      l = leakyf(v.x); r0 = fmaf(l, l, r0);
      l = leakyf(v.y); r1 = fmaf(l, l, r1);
      l = leakyf(v.z); r2 = fmaf(l, l, r2);
      l = leakyf(v.w); r3 = fmaf(l, l, r3);
    }
    sInvR[cap][r] = 20.f / (sqrtf((r0 + r1) + (r2 + r3)) + EPSF);
  }
  __syncthreads();
  // ---- main phase: wave 0 t2i (2 caps x 32 w); waves 1-2 i2t (36 units each) ----
  if (tid < 64) {
    const int cap = tid >> 5, w = tid & 31;
    float z[NR];
    float m0 = -1e30f, m1 = -1e30f, m2 = -1e30f, m3 = -1e30f;
#pragma unroll
    for (int j = 0; j < NR; j += 4) {
      z[j + 0] = leakyf(sS[cap][(j + 0) * 36 + w]) * sInvR[cap][j + 0]; m0 = fmaxf(m0, z[j + 0]);
      z[j + 1] = leakyf(sS[cap][(j + 1) * 36 + w]) * sInvR[cap][j + 1]; m1 = fmaxf(m1, z[j + 1]);
      z[j + 2] = leakyf(sS[cap][(j + 2) * 36 + w]) * sInvR[cap][j + 2]; m2 = fmaxf(m2, z[j + 2]);
      z[j + 3] = leakyf(sS[cap][(j + 3) * 36 + w]) * sInvR[cap][j + 3]; m3 = fmaxf(m3, z[j + 3]);
    }
    const float mz = fmaxf(fmaxf(m0, m1), fmaxf(m2, m3));
    float a0 = 0.f, a1 = 0.f, a2 = 0.f, a3 = 0.f;
#pragma unroll
    for (int j = 0; j < NR; j += 4) {
      z[j + 0] = __expf(z[j + 0] - mz); a0 += z[j + 0];
      z[j + 1] = __expf(z[j + 1] - mz); a1 += z[j + 1];
      z[j + 2] = __expf(z[j + 2] - mz); a2 += z[j + 2];
      z[j + 3] = __expf(z[j + 3] - mz); a3 += z[j + 3];
    }
    const float thr = ((a0 + a1) + (a2 + a3)) * (1.f / NR);
    float n0 = 0.f, n1 = 0.f, n2 = 0.f, n3 = 0.f;
#pragma unroll
    for (int j = 0; j < NR; j += 4) {  // num: re-read scores from LDS (no s[] kept)
      z[j + 0] = (z[j + 0] > thr) ? z[j + 0] : 0.f;
      n0 = fmaf(z[j + 0], sS[cap][(j + 0) * 36 + w], n0);
      z[j + 1] = (z[j + 1] > thr) ? z[j + 1] : 0.f;
      n1 = fmaf(z[j + 1], sS[cap][(j + 1) * 36 + w], n1);
      z[j + 2] = (z[j + 2] > thr) ? z[j + 2] : 0.f;
      n2 = fmaf(z[j + 2], sS[cap][(j + 2) * 36 + w], n2);
      z[j + 3] = (z[j + 3] > thr) ? z[j + 3] : 0.f;
      n3 = fmaf(z[j + 3], sS[cap][(j + 3) * 36 + w], n3);
    }
    const float num = (n0 + n1) + (n2 + n3);
    // triangular QF, 4-way accumulators
    float d0 = 0.f, d1 = 0.f, d2 = 0.f, d3 = 0.f;
#pragma unroll
    for (int j = 0; j < NR; ++j) {
      const int cj = j >> 2;
      float h0, h1, h2, h3;
      {
        const float4 g = *(const float4*)&sGi[j * 36 + cj * 4];
        const float ge[4] = {g.x, g.y, g.z, g.w};
        h0 = 0.5f * ge[j & 3] * z[j];
        h1 = 0.f; h2 = 0.f; h3 = 0.f;
#pragma unroll
        for (int e = 0; e < 4; ++e) {
          const int k = cj * 4 + e;
          if (k > j) h1 = fmaf(ge[e], z[k], h1);
        }
      }
#pragma unroll
      for (int c = 0; c < 9; ++c) {
        if (c > cj) {
          const float4 g = *(const float4*)&sGi[j * 36 + c * 4];
          h0 = fmaf(g.x, z[c * 4 + 0], h0);
          h1 = fmaf(g.y, z[c * 4 + 1], h1);
          h2 = fmaf(g.z, z[c * 4 + 2], h2);
          h3 = fmaf(g.w, z[c * 4 + 3], h3);
        }
      }
      const float h = (h0 + h1) + (h2 + h3);
      if ((j & 3) == 0) d0 = fmaf(z[j], h, d0);
      else if ((j & 3) == 1) d1 = fmaf(z[j], h, d1);
      else if ((j & 3) == 2) d2 = fmaf(z[j], h, d2);
      else d3 = fmaf(z[j], h, d3);
    }
    const float den2 = (d0 + d1) + (d2 + d3);
    const float val = num / (capn[(cg * 2 + cap) * NW + w] * sqrtf(2.f * den2) + 1e-30f);
    float contrib = val * (1.f / NW);
#pragma unroll
    for (int d = 1; d < 32; d <<= 1) contrib += __shfl_xor(contrib, d, 64);
    if ((tid & 31) == 0) atomicAdd(&red[cap], contrib);
  } else if (lane < 36) {
    const int u = (wv - 1) * 36 + lane;   // waves 1-2, 36 units each: u 0..71
    const int cap = u / NR, r = u - cap * NR;
    float z[NW];
    float m0 = -1e30f, m1 = -1e30f, m2 = -1e30f, m3 = -1e30f;
#pragma unroll
    for (int k = 0; k < 8; ++k) {
      const float4 v = *(const float4*)&sS[cap][r * 36 + k * 4];
      z[k * 4 + 0] = leakyf(v.x) * sInvC[cap][k * 4 + 0]; m0 = fmaxf(m0, z[k * 4 + 0]);
      z[k * 4 + 1] = leakyf(v.y) * sInvC[cap][k * 4 + 1]; m1 = fmaxf(m1, z[k * 4 + 1]);
      z[k * 4 + 2] = leakyf(v.z) * sInvC[cap][k * 4 + 2]; m2 = fmaxf(m2, z[k * 4 + 2]);
      z[k * 4 + 3] = leakyf(v.w) * sInvC[cap][k * 4 + 3]; m3 = fmaxf(m3, z[k * 4 + 3]);
    }
    const float mz = fmaxf(fmaxf(m0, m1), fmaxf(m2, m3));
    float a0 = 0.f, a1 = 0.f, a2 = 0.f, a3 = 0.f;
#pragma unroll
    for (int w = 0; w < NW; w += 4) {
      z[w + 0] = __expf(z[w + 0] - mz); a0 += z[w + 0];
      z[w + 1] = __expf(z[w + 1] - mz); a1 += z[w + 1];
      z[w + 2] = __expf(z[w + 2] - mz); a2 += z[w + 2];
      z[w + 3] = __expf(z[w + 3] - mz); a3 += z[w + 3];
    }
    const float thr = ((a0 + a1) + (a2 + a3)) * (1.f / NW);
    float n0 = 0.f, n1 = 0.f, n2 = 0.f, n3 = 0.f;
#pragma unroll
    for (int k = 0; k < 8; ++k) {  // num: re-read scores from LDS (no sr[] kept)
      const float4 v = *(const float4*)&sS[cap][r * 36 + k * 4];
      z[k * 4 + 0] = (z[k * 4 + 0] > thr) ? z[k * 4 + 0] : 0.f;
      n0 = fmaf(z[k * 4 + 0], v.x, n0);
      z[k * 4 + 1] = (z[k * 4 + 1] > thr) ? z[k * 4 + 1] : 0.f;
      n1 = fmaf(z[k * 4 + 1], v.y, n1);
      z[k * 4 + 2] = (z[k * 4 + 2] > thr) ? z[k * 4 + 2] : 0.f;
      n2 = fmaf(z[k * 4 + 2], v.z, n2);
      z[k * 4 + 3] = (z[k * 4 + 3] > thr) ? z[k * 4 + 3] : 0.f;
      n3 = fmaf(z[k * 4 + 3], v.w, n3);
    }
    const float num = (n0 + n1) + (n2 + n3);
    const float* Gp = &sGc[cap * GCP];
    float d0 = 0.f, d1 = 0.f, d2 = 0.f, d3 = 0.f;
#pragma unroll
    for (int w = 0; w < NW; ++w) {
      const int cw = w >> 2;
      float h0, h1, h2, h3;
      {
        const float4 g = *(const float4*)&Gp[w * 32 + cw * 4];
        const float ge[4] = {g.x, g.y, g.z, g.w};
        h0 = 0.5f * ge[w & 3] * z[w];
        h1 = 0.f; h2 = 0.f; h3 = 0.f;
#pragma unroll
        for (int e = 0; e < 4; ++e) {
          const int k = cw * 4 + e;
          if (k > w) h1 = fmaf(ge[e], z[k], h1);
        }
      }
#pragma unroll
      for (int c = 0; c < 8; ++c) {
        if (c > cw) {
          const float4 g = *(const float4*)&Gp[w * 32 + c * 4];
          h0 = fmaf(g.x, z[c * 4 + 0], h0);
          h1 = fmaf(g.y, z[c * 4 + 1], h1);
          h2 = fmaf(g.z, z[c * 4 + 2], h2);
          h3 = fmaf(g.w, z[c * 4 + 3], h3);
        }
      }
      const float h = (h0 + h1) + (h2 + h3);
      if ((w & 3) == 0) d0 = fmaf(z[w], h, d0);
      else if ((w & 3) == 1) d1 = fmaf(z[w], h, d1);
      else if ((w & 3) == 2) d2 = fmaf(z[w], h, d2);
      else d3 = fmaf(z[w], h, d3);
    }
    const float den2 = (d0 + d1) + (d2 + d3);
    const float val = num / (imgn[i * NR + r] * sqrtf(2.f * den2) + 1e-30f);
    sVal[u] = val * (1.f / NR);
  }
  __syncthreads();
  // ---- i2t reduction: 2 caps x 32 lanes sum the 36 per-r values ----
  if (tid < 64) {
    const int cap = tid >> 5, x = tid & 31;
    float v = sVal[cap * 36 + x];
    if (x < 4) v += sVal[cap * 36 + 32 + x];
#pragma unroll
    for (int d = 1; d < 32; d <<= 1) v += __shfl_xor(v, d, 64);
    if ((tid & 31) == 0) atomicAdd(&red[cap], v);
  }
  __syncthreads();
  if (tid < 2) out[(size_t)i * 128 + cg * 2 + tid] = red[tid];
}

extern "C" void kernel_launch(void* const* d_in, const int* in_sizes, int n_in,
                              void* d_out, int out_size, void* d_ws, size_t ws_size,
                              hipStream_t stream) {
  (void)in_sizes; (void)n_in; (void)out_size; (void)ws_size;
  const float* images = (const float*)d_in[0];
  const float* captions = (const float*)d_in[1];
  float* out = (float*)d_out;

  char* wb = (char*)d_ws;
  _Float16* Ahf = (_Float16*)wb; wb += (size_t)4608 * 1024 * 2;
  _Float16* Alf = (_Float16*)wb; wb += (size_t)4608 * 1024 * 2;
  _Float16* Bhf = (_Float16*)wb; wb += (size_t)4096 * 1024 * 2;
  _Float16* Blf = (_Float16*)wb; wb += (size_t)4096 * 1024 * 2;
  float* Gimg = (float*)wb; wb += (size_t)128 * NR * NR * 4;
  float* Gcap = (float*)wb; wb += (size_t)128 * NW * NW * 4;
  float* imgn = (float*)wb; wb += (size_t)128 * NR * 4;
  float* capn = (float*)wb; wb += (size_t)128 * NW * 4;
  float* C = (float*)wb;

  prep_kernel<<<256, 256, 0, stream>>>(images, captions, Gimg, Gcap, imgn, capn,
                                       Ahf, Alf, Bhf, Blf);
  mfma_gemm_kernel<<<1152, 256, 0, stream>>>(Ahf, Alf, Bhf, Blf, C);
  fused_attn_kernel<<<dim3(128, 64), 192, 0, stream>>>(C, Gimg, Gcap, imgn, capn, out);
}

// Round 13
// 235.569 us; speedup vs baseline: 1.2267x; 1.2267x over previous
//
#include <hip/hip_runtime.h>
#include <math.h>

#define NR 36
#define NW 32
#define DD 1024
#define EPSF 1e-8f

typedef _Float16 f16x8 __attribute__((ext_vector_type(8)));
typedef float f32x16 __attribute__((ext_vector_type(16)));
#define MFMA32(a, b, c) __builtin_amdgcn_mfma_f32_32x32x16_f16((a), (b), (c), 0, 0, 0)
#define GLD16(srcp, dstp)                                                              \
  __builtin_amdgcn_global_load_lds((const __attribute__((address_space(1))) void*)(srcp), \
                                   (__attribute__((address_space(3))) void*)(dstp), 16, 0, 0)

__device__ __forceinline__ float leakyf(float x) { return x > 0.f ? x : 0.1f * x; }

// ============ prep v3: hi-plane only (A and B); XOR-swizzled gram LDS; T14 async-stage =====
__global__ __launch_bounds__(256) void prep_kernel(
    const float* __restrict__ img, const float* __restrict__ cap,
    float* __restrict__ Gimg, float* __restrict__ Gcap,
    float* __restrict__ imgn, float* __restrict__ capn,
    _Float16* __restrict__ Ahf, _Float16* __restrict__ Alf,
    _Float16* __restrict__ Bhf, _Float16* __restrict__ Blf) {
  __shared__ float sA[2][NR][64];
  const int t = threadIdx.x;
  if (blockIdx.x < 128) {
    const int i = blockIdx.x;
    const float* A = img + (size_t)i * NR * DD;
    int ti = 0, tj = 0;
    const bool active = t < 171;  // 18*19/2 upper-tri 2x2 tiles
    if (active) {
      int rem = t, rl = 18;
      while (rem >= rl) { rem -= rl; ++ti; --rl; }
      tj = ti + rem;
    }
    const int a0 = 2 * ti, a1 = 2 * ti + 1, b0 = 2 * tj, b1 = 2 * tj + 1;
    const int sza = ti & 7, szb = tj & 7;
    const int kq8_1 = t / NR, r1 = t - kq8_1 * NR;
    const bool has2 = t < 32;
    const int s2 = t + 256;
    const int kq8_2 = s2 / NR, r2 = s2 - kq8_2 * NR;
    float4 p0a, p1a, p0b, p1b;
    float g00 = 0.f, g01 = 0.f, g10 = 0.f, g11 = 0.f;

    auto loadRegs = [&](int idx) {
      const int k0 = idx * 64;
      p0a = *(const float4*)(A + r1 * DD + k0 + kq8_1 * 8);
      p1a = *(const float4*)(A + r1 * DD + k0 + kq8_1 * 8 + 4);
      if (has2) {
        p0b = *(const float4*)(A + r2 * DD + k0 + kq8_2 * 8);
        p1b = *(const float4*)(A + r2 * DD + k0 + kq8_2 * 8 + 4);
      }
    };
    auto cw = [&](int idx, int cur) {
      const int k0 = idx * 64;
      {
        const float a[8] = {p0a.x, p0a.y, p0a.z, p0a.w, p1a.x, p1a.y, p1a.z, p1a.w};
        f16x8 hv;
#pragma unroll
        for (int j = 0; j < 8; ++j) hv[j] = (_Float16)a[j];
        const int m = i * NR + r1, mt = m >> 5, ml = m & 31;
        const int kk = k0 + kq8_1 * 8;
        const size_t fo = (((size_t)mt * 128 + (kk >> 3)) * 32 + ml) * 8;
        *(f16x8*)(Ahf + fo) = hv;
        const int sw = (r1 >> 1) & 7;
        *(float4*)&sA[cur][r1][((2 * kq8_1) ^ sw) * 4] = p0a;
        *(float4*)&sA[cur][r1][((2 * kq8_1 + 1) ^ sw) * 4] = p1a;
      }
      if (has2) {
        const float a[8] = {p0b.x, p0b.y, p0b.z, p0b.w, p1b.x, p1b.y, p1b.z, p1b.w};
        f16x8 hv;
#pragma unroll
        for (int j = 0; j < 8; ++j) hv[j] = (_Float16)a[j];
        const int m = i * NR + r2, mt = m >> 5, ml = m & 31;
        const int kk = k0 + kq8_2 * 8;
        const size_t fo = (((size_t)mt * 128 + (kk >> 3)) * 32 + ml) * 8;
        *(f16x8*)(Ahf + fo) = hv;
        const int sw = (r2 >> 1) & 7;
        *(float4*)&sA[cur][r2][((2 * kq8_2) ^ sw) * 4] = p0b;
        *(float4*)&sA[cur][r2][((2 * kq8_2 + 1) ^ sw) * 4] = p1b;
      }
    };

    loadRegs(0);
    for (int idx = 0; idx < 16; ++idx) {
      const int cur = idx & 1;
      cw(idx, cur);
      if (idx < 15) loadRegs(idx + 1);
      __syncthreads();
      if (active) {
#pragma unroll
        for (int k = 0; k < 16; ++k) {
          const float4 va0 = *(const float4*)&sA[cur][a0][(k ^ sza) * 4];
          const float4 va1 = *(const float4*)&sA[cur][a1][(k ^ sza) * 4];
          const float4 vb0 = *(const float4*)&sA[cur][b0][(k ^ szb) * 4];
          const float4 vb1 = *(const float4*)&sA[cur][b1][(k ^ szb) * 4];
          g00 = fmaf(va0.x, vb0.x, g00); g00 = fmaf(va0.y, vb0.y, g00);
          g00 = fmaf(va0.z, vb0.z, g00); g00 = fmaf(va0.w, vb0.w, g00);
          g01 = fmaf(va0.x, vb1.x, g01); g01 = fmaf(va0.y, vb1.y, g01);
          g01 = fmaf(va0.z, vb1.z, g01); g01 = fmaf(va0.w, vb1.w, g01);
          g10 = fmaf(va1.x, vb0.x, g10); g10 = fmaf(va1.y, vb0.y, g10);
          g10 = fmaf(va1.z, vb0.z, g10); g10 = fmaf(va1.w, vb0.w, g10);
          g11 = fmaf(va1.x, vb1.x, g11); g11 = fmaf(va1.y, vb1.y, g11);
          g11 = fmaf(va1.z, vb1.z, g11); g11 = fmaf(va1.w, vb1.w, g11);
        }
      }
    }
    if (active) {
      float* Gi = Gimg + (size_t)i * NR * NR;
      Gi[a0 * NR + b0] = g00; Gi[b0 * NR + a0] = g00;
      Gi[a0 * NR + b1] = g01; Gi[b1 * NR + a0] = g01;
      Gi[a1 * NR + b0] = g10; Gi[b0 * NR + a1] = g10;
      Gi[a1 * NR + b1] = g11; Gi[b1 * NR + a1] = g11;
      if (ti == tj) {
        imgn[i * NR + a0] = fmaxf(sqrtf(g00), EPSF);
        imgn[i * NR + a1] = fmaxf(sqrtf(g11), EPSF);
      }
    }
  } else {
    const int cb = blockIdx.x - 128;
    const float* A = cap + (size_t)cb * NW * DD;
    int ti = 0, tj = 0;
    const bool active = t < 136;  // 16*17/2
    if (active) {
      int rem = t, rl = 16;
      while (rem >= rl) { rem -= rl; ++ti; --rl; }
      tj = ti + rem;
    }
    const int a0 = 2 * ti, a1 = 2 * ti + 1, b0 = 2 * tj, b1 = 2 * tj + 1;
    const int sza = ti & 7, szb = tj & 7;
    const int kq8_1 = t >> 5, r1 = t & 31;
    float4 p0a, p1a;
    float g00 = 0.f, g01 = 0.f, g10 = 0.f, g11 = 0.f;

    auto loadRegs = [&](int idx) {
      const int k0 = idx * 64;
      p0a = *(const float4*)(A + r1 * DD + k0 + kq8_1 * 8);
      p1a = *(const float4*)(A + r1 * DD + k0 + kq8_1 * 8 + 4);
    };
    auto cw = [&](int idx, int cur) {
      const int k0 = idx * 64;
      const float a[8] = {p0a.x, p0a.y, p0a.z, p0a.w, p1a.x, p1a.y, p1a.z, p1a.w};
      f16x8 hv;
#pragma unroll
      for (int j = 0; j < 8; ++j) hv[j] = (_Float16)a[j];
      const int kk = k0 + kq8_1 * 8;
      const size_t fo = (((size_t)cb * 128 + (kk >> 3)) * 32 + r1) * 8;
      *(f16x8*)(Bhf + fo) = hv;  // hi plane only
      const int sw = (r1 >> 1) & 7;
      *(float4*)&sA[cur][r1][((2 * kq8_1) ^ sw) * 4] = p0a;
      *(float4*)&sA[cur][r1][((2 * kq8_1 + 1) ^ sw) * 4] = p1a;
    };

    loadRegs(0);
    for (int idx = 0; idx < 16; ++idx) {
      const int cur = idx & 1;
      cw(idx, cur);
      if (idx < 15) loadRegs(idx + 1);
      __syncthreads();
      if (active) {
#pragma unroll
        for (int k = 0; k < 16; ++k) {
          const float4 va0 = *(const float4*)&sA[cur][a0][(k ^ sza) * 4];
          const float4 va1 = *(const float4*)&sA[cur][a1][(k ^ sza) * 4];
          const float4 vb0 = *(const float4*)&sA[cur][b0][(k ^ szb) * 4];
          const float4 vb1 = *(const float4*)&sA[cur][b1][(k ^ szb) * 4];
          g00 = fmaf(va0.x, vb0.x, g00); g00 = fmaf(va0.y, vb0.y, g00);
          g00 = fmaf(va0.z, vb0.z, g00); g00 = fmaf(va0.w, vb0.w, g00);
          g01 = fmaf(va0.x, vb1.x, g01); g01 = fmaf(va0.y, vb1.y, g01);
          g01 = fmaf(va0.z, vb1.z, g01); g01 = fmaf(va0.w, vb1.w, g01);
          g10 = fmaf(va1.x, vb0.x, g10); g10 = fmaf(va1.y, vb0.y, g10);
          g10 = fmaf(va1.z, vb0.z, g10); g10 = fmaf(va1.w, vb0.w, g10);
          g11 = fmaf(va1.x, vb1.x, g11); g11 = fmaf(va1.y, vb1.y, g11);
          g11 = fmaf(va1.z, vb1.z, g11); g11 = fmaf(va1.w, vb1.w, g11);
        }
      }
    }
    if (active) {
      float* Gc = Gcap + (size_t)cb * NW * NW;
      Gc[a0 * NW + b0] = g00; Gc[b0 * NW + a0] = g00;
      Gc[a0 * NW + b1] = g01; Gc[b1 * NW + a0] = g01;
      Gc[a1 * NW + b0] = g10; Gc[b0 * NW + a1] = g10;
      Gc[a1 * NW + b1] = g11; Gc[b1 * NW + a1] = g11;
      if (ti == tj) {
        capn[cb * NW + a0] = fmaxf(sqrtf(g00), EPSF);
        capn[cb * NW + a1] = fmaxf(sqrtf(g11), EPSF);
      }
    }
  }
}

// ============ MFMA GEMM v6: BK=64 phases — 1 barrier per 16 MFMA (kept, ~60us) ============
__device__ __forceinline__ void gemm_loadA(const _Float16* __restrict__ Ahf, int Mt0, int kt,
                                           int kb, int lm, f16x8 ar[2][2]) {
#pragma unroll
  for (int mt = 0; mt < 2; ++mt)
#pragma unroll
    for (int ks = 0; ks < 2; ++ks) {
      const size_t o = (((size_t)(Mt0 + mt) * 128) + kt * 4 + ks * 2 + kb) * 256 + lm * 8;
      ar[mt][ks] = *(const f16x8*)(Ahf + o);
    }
}

__global__ __launch_bounds__(256) void mfma_gemm_kernel(
    const _Float16* __restrict__ Ahf, const _Float16* __restrict__ Alf,
    const _Float16* __restrict__ Bhf, const _Float16* __restrict__ Blf, float* __restrict__ C) {
  __shared__ _Float16 sB[2][8192];  // 2 bufs x (2 kt x 8KB): [kh*4096 + (nb*4+kq)*256 + lm*8]
  const int bid0 = blockIdx.x;
  const int bid = (bid0 & 7) * 144 + (bid0 >> 3);  // T1 xb-chunked XCD swizzle (1152=8*144)
  const int yb = bid & 31, xb = bid >> 5;
  const int n0b = yb * 4;
  const int tid = threadIdx.x;
  const int wv = tid >> 6, lane = tid & 63;
  const int lm = lane & 31, kb = lane >> 5;
  const int Mt0 = xb * 4 + (wv >> 1) * 2;
  const int nb0 = (wv & 1) * 2;
  (void)Alf; (void)Blf;

  auto stageB2 = [&](int p, int buf) {  // stage kts 2p, 2p+1
#pragma unroll
    for (int u = 0; u < 4; ++u) {
      const int kt = 2 * p + (u >> 1);
      const int cpb = wv * 4 + (u & 1) * 2;
      const int cp = cpb + kb;
      const int nb = cp >> 2, kq = cp & 3;
      const _Float16* src = Bhf + (((size_t)(n0b + nb) * 128 + kt * 4 + kq) * 32 + lm) * 8;
      GLD16(src, &sB[buf][(u >> 1) * 4096 + cpb * 256]);
    }
  };

  f32x16 acc[2][2];
#pragma unroll
  for (int a = 0; a < 2; ++a)
#pragma unroll
    for (int b = 0; b < 2; ++b) acc[a][b] = {};
  f16x8 arE[2][2][2], arO[2][2][2];  // [kh][mt][ks]

  auto loadA2 = [&](int p, f16x8 ar[2][2][2]) {
#pragma unroll
    for (int kh = 0; kh < 2; ++kh) gemm_loadA(Ahf, Mt0, 2 * p + kh, kb, lm, ar[kh]);
  };
  auto computeHalf = [&](const _Float16* sb, const f16x8 ar[2][2]) {
#pragma unroll
    for (int ks = 0; ks < 2; ++ks)
#pragma unroll
      for (int ntl = 0; ntl < 2; ++ntl) {
        const int nt = nb0 + ntl;
        const int co = (nt * 4 + ks * 2 + kb) * 256 + lm * 8;
        const f16x8 bh = *(const f16x8*)&sb[co];
        acc[0][ntl] = MFMA32(ar[0][ks], bh, acc[0][ntl]);
        acc[1][ntl] = MFMA32(ar[1][ks], bh, acc[1][ntl]);
      }
  };
  auto computeP = [&](const _Float16* sb, const f16x8 ar[2][2][2]) {
    computeHalf(sb, ar[0]);
    computeHalf(sb + 4096, ar[1]);
  };

  stageB2(0, 0);
  loadA2(0, arE);
  for (int pp = 0; pp < 8; ++pp) {
    const int p = 2 * pp;
    __syncthreads();  // stage(p) + A(p) landed
    stageB2(p + 1, 1);
    loadA2(p + 1, arO);
    computeP(sB[0], arE);
    __syncthreads();
    if (p + 2 < 16) {
      stageB2(p + 2, 0);
      loadA2(p + 2, arE);
    }
    computeP(sB[1], arO);
  }
  // epilogue: C/D layout col=lane&31, row=(q&3)+8*(q>>2)+4*kb ; C[((il*128+c)*36+r)*32+w]
#pragma unroll
  for (int mt = 0; mt < 2; ++mt)
#pragma unroll
    for (int ntl = 0; ntl < 2; ++ntl) {
      const int cc = n0b + nb0 + ntl;
      const f32x16 a = acc[mt][ntl];
#pragma unroll
      for (int q = 0; q < 16; ++q) {
        const int row32 = (q & 3) + 8 * (q >> 2) + 4 * kb;
        const int m = (Mt0 + mt) * 32 + row32;
        const int il = m / NR, r = m - il * NR;
        C[((size_t)il * 128 + cc) * (NR * NW) + r * NW + lm] = a[q];
      }
    }
}

// ============ fused v11 = r10's v8 EXACTLY (launch_bounds(192,4): VGPR 64 + spills beat
// fewer-waves — r12 matrix: {64reg+spill,35%occ,94.5us} vs {112reg,17%occ,152us}) =========
#define GCP 1040
__global__ __launch_bounds__(192, 4) void fused_attn_kernel(
    const float* __restrict__ C, const float* __restrict__ Gimg, const float* __restrict__ Gcap,
    const float* __restrict__ imgn, const float* __restrict__ capn, float* __restrict__ out) {
  const int i = blockIdx.x;
  const int cg = blockIdx.y;  // 0..63, 2 caps per block
  const int tid = threadIdx.x;
  const int wv = tid >> 6, lane = tid & 63;
  __shared__ float sS[2][NR * 36];   // scores, row stride 36
  __shared__ float sGi[NR * NR];     // image gram 36x36 (broadcast reads)
  __shared__ float sGc[2 * GCP];     // caption grams 32x32, padded stride 1040
  __shared__ float sInvR[2][NR];
  __shared__ float sInvC[2][NW];
  __shared__ float sVal[72];
  __shared__ float red[2];
  if (tid < 2) red[tid] = 0.f;
  // ---- stage scores + grams ----
  const float* Cp = C + ((size_t)i * 128 + cg * 2) * (NR * NW);
  for (int t = tid; t < 2 * 288; t += 192) {
    const int cap = t / 288, rem = t - cap * 288;
    const int r = rem >> 3, wq = rem & 7;
    const float4 v = *(const float4*)(Cp + cap * (NR * NW) + r * NW + wq * 4);
    *(float4*)&sS[cap][r * 36 + wq * 4] = v;
  }
  const float* Gi = Gimg + (size_t)i * (NR * NR);
  for (int t = tid; t < 324; t += 192) *(float4*)&sGi[t * 4] = *(const float4*)(Gi + t * 4);
  const float* Gc0 = Gcap + (size_t)(cg * 2) * (NW * NW);
  for (int t = tid; t < 512; t += 192) {
    const int cap = t >> 8, q = t & 255;
    *(float4*)&sGc[cap * GCP + q * 4] = *(const float4*)(Gc0 + cap * (NW * NW) + q * 4);
  }
  __syncthreads();
  // ---- norm phase: col-norms (tid<64: 2 caps x 32w) + row-norms (tid 64..135: 2x36) ----
  if (tid < 64) {
    const int cap = tid >> 5, w = tid & 31;
    float c0 = 0.f, c1 = 0.f, c2 = 0.f, c3 = 0.f;
#pragma unroll
    for (int j = 0; j < NR; j += 4) {
      const float l0 = leakyf(sS[cap][(j + 0) * 36 + w]);
      const float l1 = leakyf(sS[cap][(j + 1) * 36 + w]);
      const float l2 = leakyf(sS[cap][(j + 2) * 36 + w]);
      const float l3 = leakyf(sS[cap][(j + 3) * 36 + w]);
      c0 = fmaf(l0, l0, c0); c1 = fmaf(l1, l1, c1);
      c2 = fmaf(l2, l2, c2); c3 = fmaf(l3, l3, c3);
    }
    sInvC[cap][w] = 20.f / (sqrtf((c0 + c1) + (c2 + c3)) + EPSF);
  } else if (tid < 136) {
    const int u = tid - 64;
    const int cap = u / NR, r = u - cap * NR;
    float r0 = 0.f, r1 = 0.f, r2 = 0.f, r3 = 0.f;
#pragma unroll
    for (int k = 0; k < 8; ++k) {
      const float4 v = *(const float4*)&sS[cap][r * 36 + k * 4];
      float l;
      l = leakyf(v.x); r0 = fmaf(l, l, r0);
      l = leakyf(v.y); r1 = fmaf(l, l, r1);
      l = leakyf(v.z); r2 = fmaf(l, l, r2);
      l = leakyf(v.w); r3 = fmaf(l, l, r3);
    }
    sInvR[cap][r] = 20.f / (sqrtf((r0 + r1) + (r2 + r3)) + EPSF);
  }
  __syncthreads();
  // ---- main phase: wave 0 t2i (2 caps x 32 w); waves 1-2 i2t (36 units each) ----
  if (tid < 64) {
    const int cap = tid >> 5, w = tid & 31;
    float z[NR];
    float m0 = -1e30f, m1 = -1e30f, m2 = -1e30f, m3 = -1e30f;
#pragma unroll
    for (int j = 0; j < NR; j += 4) {
      z[j + 0] = leakyf(sS[cap][(j + 0) * 36 + w]) * sInvR[cap][j + 0]; m0 = fmaxf(m0, z[j + 0]);
      z[j + 1] = leakyf(sS[cap][(j + 1) * 36 + w]) * sInvR[cap][j + 1]; m1 = fmaxf(m1, z[j + 1]);
      z[j + 2] = leakyf(sS[cap][(j + 2) * 36 + w]) * sInvR[cap][j + 2]; m2 = fmaxf(m2, z[j + 2]);
      z[j + 3] = leakyf(sS[cap][(j + 3) * 36 + w]) * sInvR[cap][j + 3]; m3 = fmaxf(m3, z[j + 3]);
    }
    const float mz = fmaxf(fmaxf(m0, m1), fmaxf(m2, m3));
    float a0 = 0.f, a1 = 0.f, a2 = 0.f, a3 = 0.f;
#pragma unroll
    for (int j = 0; j < NR; j += 4) {
      z[j + 0] = __expf(z[j + 0] - mz); a0 += z[j + 0];
      z[j + 1] = __expf(z[j + 1] - mz); a1 += z[j + 1];
      z[j + 2] = __expf(z[j + 2] - mz); a2 += z[j + 2];
      z[j + 3] = __expf(z[j + 3] - mz); a3 += z[j + 3];
    }
    const float thr = ((a0 + a1) + (a2 + a3)) * (1.f / NR);
    float n0 = 0.f, n1 = 0.f, n2 = 0.f, n3 = 0.f;
#pragma unroll
    for (int j = 0; j < NR; j += 4) {  // num: re-read scores from LDS (no s[] kept)
      z[j + 0] = (z[j + 0] > thr) ? z[j + 0] : 0.f;
      n0 = fmaf(z[j + 0], sS[cap][(j + 0) * 36 + w], n0);
      z[j + 1] = (z[j + 1] > thr) ? z[j + 1] : 0.f;
      n1 = fmaf(z[j + 1], sS[cap][(j + 1) * 36 + w], n1);
      z[j + 2] = (z[j + 2] > thr) ? z[j + 2] : 0.f;
      n2 = fmaf(z[j + 2], sS[cap][(j + 2) * 36 + w], n2);
      z[j + 3] = (z[j + 3] > thr) ? z[j + 3] : 0.f;
      n3 = fmaf(z[j + 3], sS[cap][(j + 3) * 36 + w], n3);
    }
    const float num = (n0 + n1) + (n2 + n3);
    // triangular QF, 4-way accumulators
    float d0 = 0.f, d1 = 0.f, d2 = 0.f, d3 = 0.f;
#pragma unroll
    for (int j = 0; j < NR; ++j) {
      const int cj = j >> 2;
      float h0, h1, h2, h3;
      {
        const float4 g = *(const float4*)&sGi[j * 36 + cj * 4];
        const float ge[4] = {g.x, g.y, g.z, g.w};
        h0 = 0.5f * ge[j & 3] * z[j];
        h1 = 0.f; h2 = 0.f; h3 = 0.f;
#pragma unroll
        for (int e = 0; e < 4; ++e) {
          const int k = cj * 4 + e;
          if (k > j) h1 = fmaf(ge[e], z[k], h1);
        }
      }
#pragma unroll
      for (int c = 0; c < 9; ++c) {
        if (c > cj) {
          const float4 g = *(const float4*)&sGi[j * 36 + c * 4];
          h0 = fmaf(g.x, z[c * 4 + 0], h0);
          h1 = fmaf(g.y, z[c * 4 + 1], h1);
          h2 = fmaf(g.z, z[c * 4 + 2], h2);
          h3 = fmaf(g.w, z[c * 4 + 3], h3);
        }
      }
      const float h = (h0 + h1) + (h2 + h3);
      if ((j & 3) == 0) d0 = fmaf(z[j], h, d0);
      else if ((j & 3) == 1) d1 = fmaf(z[j], h, d1);
      else if ((j & 3) == 2) d2 = fmaf(z[j], h, d2);
      else d3 = fmaf(z[j], h, d3);
    }
    const float den2 = (d0 + d1) + (d2 + d3);
    const float val = num / (capn[(cg * 2 + cap) * NW + w] * sqrtf(2.f * den2) + 1e-30f);
    float contrib = val * (1.f / NW);
#pragma unroll
    for (int d = 1; d < 32; d <<= 1) contrib += __shfl_xor(contrib, d, 64);
    if ((tid & 31) == 0) atomicAdd(&red[cap], contrib);
  } else if (lane < 36) {
    const int u = (wv - 1) * 36 + lane;   // waves 1-2, 36 units each: u 0..71
    const int cap = u / NR, r = u - cap * NR;
    float z[NW];
    float m0 = -1e30f, m1 = -1e30f, m2 = -1e30f, m3 = -1e30f;
#pragma unroll
    for (int k = 0; k < 8; ++k) {
      const float4 v = *(const float4*)&sS[cap][r * 36 + k * 4];
      z[k * 4 + 0] = leakyf(v.x) * sInvC[cap][k * 4 + 0]; m0 = fmaxf(m0, z[k * 4 + 0]);
      z[k * 4 + 1] = leakyf(v.y) * sInvC[cap][k * 4 + 1]; m1 = fmaxf(m1, z[k * 4 + 1]);
      z[k * 4 + 2] = leakyf(v.z) * sInvC[cap][k * 4 + 2]; m2 = fmaxf(m2, z[k * 4 + 2]);
      z[k * 4 + 3] = leakyf(v.w) * sInvC[cap][k * 4 + 3]; m3 = fmaxf(m3, z[k * 4 + 3]);
    }
    const float mz = fmaxf(fmaxf(m0, m1), fmaxf(m2, m3));
    float a0 = 0.f, a1 = 0.f, a2 = 0.f, a3 = 0.f;
#pragma unroll
    for (int w = 0; w < NW; w += 4) {
      z[w + 0] = __expf(z[w + 0] - mz); a0 += z[w + 0];
      z[w + 1] = __expf(z[w + 1] - mz); a1 += z[w + 1];
      z[w + 2] = __expf(z[w + 2] - mz); a2 += z[w + 2];
      z[w + 3] = __expf(z[w + 3] - mz); a3 += z[w + 3];
    }
    const float thr = ((a0 + a1) + (a2 + a3)) * (1.f / NW);
    float n0 = 0.f, n1 = 0.f, n2 = 0.f, n3 = 0.f;
#pragma unroll
    for (int k = 0; k < 8; ++k) {  // num: re-read scores from LDS (no sr[] kept)
      const float4 v = *(const float4*)&sS[cap][r * 36 + k * 4];
      z[k * 4 + 0] = (z[k * 4 + 0] > thr) ? z[k * 4 + 0] : 0.f;
      n0 = fmaf(z[k * 4 + 0], v.x, n0);
      z[k * 4 + 1] = (z[k * 4 + 1] > thr) ? z[k * 4 + 1] : 0.f;
      n1 = fmaf(z[k * 4 + 1], v.y, n1);
      z[k * 4 + 2] = (z[k * 4 + 2] > thr) ? z[k * 4 + 2] : 0.f;
      n2 = fmaf(z[k * 4 + 2], v.z, n2);
      z[k * 4 + 3] = (z[k * 4 + 3] > thr) ? z[k * 4 + 3] : 0.f;
      n3 = fmaf(z[k * 4 + 3], v.w, n3);
    }
    const float num = (n0 + n1) + (n2 + n3);
    const float* Gp = &sGc[cap * GCP];
    float d0 = 0.f, d1 = 0.f, d2 = 0.f, d3 = 0.f;
#pragma unroll
    for (int w = 0; w < NW; ++w) {
      const int cw = w >> 2;
      float h0, h1, h2, h3;
      {
        const float4 g = *(const float4*)&Gp[w * 32 + cw * 4];
        const float ge[4] = {g.x, g.y, g.z, g.w};
        h0 = 0.5f * ge[w & 3] * z[w];
        h1 = 0.f; h2 = 0.f; h3 = 0.f;
#pragma unroll
        for (int e = 0; e < 4; ++e) {
          const int k = cw * 4 + e;
          if (k > w) h1 = fmaf(ge[e], z[k], h1);
        }
      }
#pragma unroll
      for (int c = 0; c < 8; ++c) {
        if (c > cw) {
          const float4 g = *(const float4*)&Gp[w * 32 + c * 4];
          h0 = fmaf(g.x, z[c * 4 + 0], h0);
          h1 = fmaf(g.y, z[c * 4 + 1], h1);
          h2 = fmaf(g.z, z[c * 4 + 2], h2);
          h3 = fmaf(g.w, z[c * 4 + 3], h3);
        }
      }
      const float h = (h0 + h1) + (h2 + h3);
      if ((w & 3) == 0) d0 = fmaf(z[w], h, d0);
      else if ((w & 3) == 1) d1 = fmaf(z[w], h, d1);
      else if ((w & 3) == 2) d2 = fmaf(z[w], h, d2);
      else d3 = fmaf(z[w], h, d3);
    }
    const float den2 = (d0 + d1) + (d2 + d3);
    const float val = num / (imgn[i * NR + r] * sqrtf(2.f * den2) + 1e-30f);
    sVal[u] = val * (1.f / NR);
  }
  __syncthreads();
  // ---- i2t reduction: 2 caps x 32 lanes sum the 36 per-r values ----
  if (tid < 64) {
    const int cap = tid >> 5, x = tid & 31;
    float v = sVal[cap * 36 + x];
    if (x < 4) v += sVal[cap * 36 + 32 + x];
#pragma unroll
    for (int d = 1; d < 32; d <<= 1) v += __shfl_xor(v, d, 64);
    if ((tid & 31) == 0) atomicAdd(&red[cap], v);
  }
  __syncthreads();
  if (tid < 2) out[(size_t)i * 128 + cg * 2 + tid] = red[tid];
}

extern "C" void kernel_launch(void* const* d_in, const int* in_sizes, int n_in,
                              void* d_out, int out_size, void* d_ws, size_t ws_size,
                              hipStream_t stream) {
  (void)in_sizes; (void)n_in; (void)out_size; (void)ws_size;
  const float* images = (const float*)d_in[0];
  const float* captions = (const float*)d_in[1];
  float* out = (float*)d_out;

  char* wb = (char*)d_ws;
  _Float16* Ahf = (_Float16*)wb; wb += (size_t)4608 * 1024 * 2;
  _Float16* Alf = (_Float16*)wb; wb += (size_t)4608 * 1024 * 2;
  _Float16* Bhf = (_Float16*)wb; wb += (size_t)4096 * 1024 * 2;
  _Float16* Blf = (_Float16*)wb; wb += (size_t)4096 * 1024 * 2;
  float* Gimg = (float*)wb; wb += (size_t)128 * NR * NR * 4;
  float* Gcap = (float*)wb; wb += (size_t)128 * NW * NW * 4;
  float* imgn = (float*)wb; wb += (size_t)128 * NR * 4;
  float* capn = (float*)wb; wb += (size_t)128 * NW * 4;
  float* C = (float*)wb;

  prep_kernel<<<256, 256, 0, stream>>>(images, captions, Gimg, Gcap, imgn, capn,
                                       Ahf, Alf, Bhf, Blf);
  mfma_gemm_kernel<<<1152, 256, 0, stream>>>(Ahf, Alf, Bhf, Blf, C);
  fused_attn_kernel<<<dim3(128, 64), 192, 0, stream>>>(C, Gimg, Gcap, imgn, capn, out);
}

// Round 14
// 227.041 us; speedup vs baseline: 1.2728x; 1.0376x over previous
//
#include <hip/hip_runtime.h>
#include <math.h>

#define NR 36
#define NW 32
#define DD 1024
#define EPSF 1e-8f

typedef _Float16 f16x8 __attribute__((ext_vector_type(8)));
typedef float f32x16 __attribute__((ext_vector_type(16)));
#define MFMA32(a, b, c) __builtin_amdgcn_mfma_f32_32x32x16_f16((a), (b), (c), 0, 0, 0)
#define GLD16(srcp, dstp)                                                              \
  __builtin_amdgcn_global_load_lds((const __attribute__((address_space(1))) void*)(srcp), \
                                   (__attribute__((address_space(3))) void*)(dstp), 16, 0, 0)

__device__ __forceinline__ float leakyf(float x) { return x > 0.f ? x : 0.1f * x; }

#define GI_SLAB (128 * NR * NR)   // 165888 floats per k-slab
#define GC_SLAB (128 * NW * NW)   // 131072 floats per k-slab

// ============ prep v4: 4-way K-split — grid 1024 (4 blocks/CU), partial grams to slabs ====
// r13: prep was 1 block/CU (zero TLP), 16 serial barrier phases. v4: each block does 256
// dims (4 phases); partial gram -> slab kh; fused sums slabs + computes norms inline.
__global__ __launch_bounds__(256) void prep_kernel(
    const float* __restrict__ img, const float* __restrict__ cap,
    float* __restrict__ Gimg, float* __restrict__ Gcap,
    _Float16* __restrict__ Ahf, _Float16* __restrict__ Bhf) {
  __shared__ float sA[2][NR][64];
  const int t = threadIdx.x;
  const int x = blockIdx.x;
  if (x < 512) {
    const int i = x >> 2, kh = x & 3;   // image i, k-range [kh*256, kh*256+256)
    const float* A = img + (size_t)i * NR * DD;
    int ti = 0, tj = 0;
    const bool active = t < 171;  // 18*19/2 upper-tri 2x2 tiles
    if (active) {
      int rem = t, rl = 18;
      while (rem >= rl) { rem -= rl; ++ti; --rl; }
      tj = ti + rem;
    }
    const int a0 = 2 * ti, a1 = 2 * ti + 1, b0 = 2 * tj, b1 = 2 * tj + 1;
    const int sza = ti & 7, szb = tj & 7;
    const int kq8_1 = t / NR, r1 = t - kq8_1 * NR;
    const bool has2 = t < 32;
    const int s2 = t + 256;
    const int kq8_2 = s2 / NR, r2 = s2 - kq8_2 * NR;
    float4 p0a, p1a, p0b, p1b;
    float g00 = 0.f, g01 = 0.f, g10 = 0.f, g11 = 0.f;

    auto loadRegs = [&](int idx) {
      const int k0 = idx * 64;
      p0a = *(const float4*)(A + r1 * DD + k0 + kq8_1 * 8);
      p1a = *(const float4*)(A + r1 * DD + k0 + kq8_1 * 8 + 4);
      if (has2) {
        p0b = *(const float4*)(A + r2 * DD + k0 + kq8_2 * 8);
        p1b = *(const float4*)(A + r2 * DD + k0 + kq8_2 * 8 + 4);
      }
    };
    auto cw = [&](int idx, int cur) {
      const int k0 = idx * 64;
      {
        const float a[8] = {p0a.x, p0a.y, p0a.z, p0a.w, p1a.x, p1a.y, p1a.z, p1a.w};
        f16x8 hv;
#pragma unroll
        for (int j = 0; j < 8; ++j) hv[j] = (_Float16)a[j];
        const int m = i * NR + r1, mt = m >> 5, ml = m & 31;
        const int kk = k0 + kq8_1 * 8;
        const size_t fo = (((size_t)mt * 128 + (kk >> 3)) * 32 + ml) * 8;
        *(f16x8*)(Ahf + fo) = hv;
        const int sw = (r1 >> 1) & 7;
        *(float4*)&sA[cur][r1][((2 * kq8_1) ^ sw) * 4] = p0a;
        *(float4*)&sA[cur][r1][((2 * kq8_1 + 1) ^ sw) * 4] = p1a;
      }
      if (has2) {
        const float a[8] = {p0b.x, p0b.y, p0b.z, p0b.w, p1b.x, p1b.y, p1b.z, p1b.w};
        f16x8 hv;
#pragma unroll
        for (int j = 0; j < 8; ++j) hv[j] = (_Float16)a[j];
        const int m = i * NR + r2, mt = m >> 5, ml = m & 31;
        const int kk = k0 + kq8_2 * 8;
        const size_t fo = (((size_t)mt * 128 + (kk >> 3)) * 32 + ml) * 8;
        *(f16x8*)(Ahf + fo) = hv;
        const int sw = (r2 >> 1) & 7;
        *(float4*)&sA[cur][r2][((2 * kq8_2) ^ sw) * 4] = p0b;
        *(float4*)&sA[cur][r2][((2 * kq8_2 + 1) ^ sw) * 4] = p1b;
      }
    };

    const int idx0 = kh * 4;
    loadRegs(idx0);
    for (int l = 0; l < 4; ++l) {
      const int idx = idx0 + l;
      const int cur = l & 1;
      cw(idx, cur);
      if (l < 3) loadRegs(idx + 1);
      __syncthreads();
      if (active) {
#pragma unroll
        for (int k = 0; k < 16; ++k) {
          const float4 va0 = *(const float4*)&sA[cur][a0][(k ^ sza) * 4];
          const float4 va1 = *(const float4*)&sA[cur][a1][(k ^ sza) * 4];
          const float4 vb0 = *(const float4*)&sA[cur][b0][(k ^ szb) * 4];
          const float4 vb1 = *(const float4*)&sA[cur][b1][(k ^ szb) * 4];
          g00 = fmaf(va0.x, vb0.x, g00); g00 = fmaf(va0.y, vb0.y, g00);
          g00 = fmaf(va0.z, vb0.z, g00); g00 = fmaf(va0.w, vb0.w, g00);
          g01 = fmaf(va0.x, vb1.x, g01); g01 = fmaf(va0.y, vb1.y, g01);
          g01 = fmaf(va0.z, vb1.z, g01); g01 = fmaf(va0.w, vb1.w, g01);
          g10 = fmaf(va1.x, vb0.x, g10); g10 = fmaf(va1.y, vb0.y, g10);
          g10 = fmaf(va1.z, vb0.z, g10); g10 = fmaf(va1.w, vb0.w, g10);
          g11 = fmaf(va1.x, vb1.x, g11); g11 = fmaf(va1.y, vb1.y, g11);
          g11 = fmaf(va1.z, vb1.z, g11); g11 = fmaf(va1.w, vb1.w, g11);
        }
      }
      __syncthreads();
    }
    if (active) {
      float* Gi = Gimg + (size_t)kh * GI_SLAB + (size_t)i * NR * NR;
      Gi[a0 * NR + b0] = g00; Gi[b0 * NR + a0] = g00;
      Gi[a0 * NR + b1] = g01; Gi[b1 * NR + a0] = g01;
      Gi[a1 * NR + b0] = g10; Gi[b0 * NR + a1] = g10;
      Gi[a1 * NR + b1] = g11; Gi[b1 * NR + a1] = g11;
    }
  } else {
    const int xc = x - 512;
    const int cb = xc >> 2, kh = xc & 3;
    const float* A = cap + (size_t)cb * NW * DD;
    int ti = 0, tj = 0;
    const bool active = t < 136;  // 16*17/2
    if (active) {
      int rem = t, rl = 16;
      while (rem >= rl) { rem -= rl; ++ti; --rl; }
      tj = ti + rem;
    }
    const int a0 = 2 * ti, a1 = 2 * ti + 1, b0 = 2 * tj, b1 = 2 * tj + 1;
    const int sza = ti & 7, szb = tj & 7;
    const int kq8_1 = t >> 5, r1 = t & 31;
    float4 p0a, p1a;
    float g00 = 0.f, g01 = 0.f, g10 = 0.f, g11 = 0.f;

    auto loadRegs = [&](int idx) {
      const int k0 = idx * 64;
      p0a = *(const float4*)(A + r1 * DD + k0 + kq8_1 * 8);
      p1a = *(const float4*)(A + r1 * DD + k0 + kq8_1 * 8 + 4);
    };
    auto cw = [&](int idx, int cur) {
      const int k0 = idx * 64;
      const float a[8] = {p0a.x, p0a.y, p0a.z, p0a.w, p1a.x, p1a.y, p1a.z, p1a.w};
      f16x8 hv;
#pragma unroll
      for (int j = 0; j < 8; ++j) hv[j] = (_Float16)a[j];
      const int kk = k0 + kq8_1 * 8;
      const size_t fo = (((size_t)cb * 128 + (kk >> 3)) * 32 + r1) * 8;
      *(f16x8*)(Bhf + fo) = hv;
      const int sw = (r1 >> 1) & 7;
      *(float4*)&sA[cur][r1][((2 * kq8_1) ^ sw) * 4] = p0a;
      *(float4*)&sA[cur][r1][((2 * kq8_1 + 1) ^ sw) * 4] = p1a;
    };

    const int idx0 = kh * 4;
    loadRegs(idx0);
    for (int l = 0; l < 4; ++l) {
      const int idx = idx0 + l;
      const int cur = l & 1;
      cw(idx, cur);
      if (l < 3) loadRegs(idx + 1);
      __syncthreads();
      if (active) {
#pragma unroll
        for (int k = 0; k < 16; ++k) {
          const float4 va0 = *(const float4*)&sA[cur][a0][(k ^ sza) * 4];
          const float4 va1 = *(const float4*)&sA[cur][a1][(k ^ sza) * 4];
          const float4 vb0 = *(const float4*)&sA[cur][b0][(k ^ szb) * 4];
          const float4 vb1 = *(const float4*)&sA[cur][b1][(k ^ szb) * 4];
          g00 = fmaf(va0.x, vb0.x, g00); g00 = fmaf(va0.y, vb0.y, g00);
          g00 = fmaf(va0.z, vb0.z, g00); g00 = fmaf(va0.w, vb0.w, g00);
          g01 = fmaf(va0.x, vb1.x, g01); g01 = fmaf(va0.y, vb1.y, g01);
          g01 = fmaf(va0.z, vb1.z, g01); g01 = fmaf(va0.w, vb1.w, g01);
          g10 = fmaf(va1.x, vb0.x, g10); g10 = fmaf(va1.y, vb0.y, g10);
          g10 = fmaf(va1.z, vb0.z, g10); g10 = fmaf(va1.w, vb0.w, g10);
          g11 = fmaf(va1.x, vb1.x, g11); g11 = fmaf(va1.y, vb1.y, g11);
          g11 = fmaf(va1.z, vb1.z, g11); g11 = fmaf(va1.w, vb1.w, g11);
        }
      }
      __syncthreads();
    }
    if (active) {
      float* Gc = Gcap + (size_t)kh * GC_SLAB + (size_t)cb * NW * NW;
      Gc[a0 * NW + b0] = g00; Gc[b0 * NW + a0] = g00;
      Gc[a0 * NW + b1] = g01; Gc[b1 * NW + a0] = g01;
      Gc[a1 * NW + b0] = g10; Gc[b0 * NW + a1] = g10;
      Gc[a1 * NW + b1] = g11; Gc[b1 * NW + a1] = g11;
    }
  }
}

// ============ MFMA GEMM v6: BK=64 phases — 1 barrier per 16 MFMA (kept, ~60us) ============
__device__ __forceinline__ void gemm_loadA(const _Float16* __restrict__ Ahf, int Mt0, int kt,
                                           int kb, int lm, f16x8 ar[2][2]) {
#pragma unroll
  for (int mt = 0; mt < 2; ++mt)
#pragma unroll
    for (int ks = 0; ks < 2; ++ks) {
      const size_t o = (((size_t)(Mt0 + mt) * 128) + kt * 4 + ks * 2 + kb) * 256 + lm * 8;
      ar[mt][ks] = *(const f16x8*)(Ahf + o);
    }
}

__global__ __launch_bounds__(256) void mfma_gemm_kernel(
    const _Float16* __restrict__ Ahf, const _Float16* __restrict__ Bhf, float* __restrict__ C) {
  __shared__ _Float16 sB[2][8192];  // 2 bufs x (2 kt x 8KB): [kh*4096 + (nb*4+kq)*256 + lm*8]
  const int bid0 = blockIdx.x;
  const int bid = (bid0 & 7) * 144 + (bid0 >> 3);  // T1 xb-chunked XCD swizzle (1152=8*144)
  const int yb = bid & 31, xb = bid >> 5;
  const int n0b = yb * 4;
  const int tid = threadIdx.x;
  const int wv = tid >> 6, lane = tid & 63;
  const int lm = lane & 31, kb = lane >> 5;
  const int Mt0 = xb * 4 + (wv >> 1) * 2;
  const int nb0 = (wv & 1) * 2;

  auto stageB2 = [&](int p, int buf) {  // stage kts 2p, 2p+1
#pragma unroll
    for (int u = 0; u < 4; ++u) {
      const int kt = 2 * p + (u >> 1);
      const int cpb = wv * 4 + (u & 1) * 2;
      const int cp = cpb + kb;
      const int nb = cp >> 2, kq = cp & 3;
      const _Float16* src = Bhf + (((size_t)(n0b + nb) * 128 + kt * 4 + kq) * 32 + lm) * 8;
      GLD16(src, &sB[buf][(u >> 1) * 4096 + cpb * 256]);
    }
  };

  f32x16 acc[2][2];
#pragma unroll
  for (int a = 0; a < 2; ++a)
#pragma unroll
    for (int b = 0; b < 2; ++b) acc[a][b] = {};
  f16x8 arE[2][2][2], arO[2][2][2];  // [kh][mt][ks]

  auto loadA2 = [&](int p, f16x8 ar[2][2][2]) {
#pragma unroll
    for (int kh = 0; kh < 2; ++kh) gemm_loadA(Ahf, Mt0, 2 * p + kh, kb, lm, ar[kh]);
  };
  auto computeHalf = [&](const _Float16* sb, const f16x8 ar[2][2]) {
#pragma unroll
    for (int ks = 0; ks < 2; ++ks)
#pragma unroll
      for (int ntl = 0; ntl < 2; ++ntl) {
        const int nt = nb0 + ntl;
        const int co = (nt * 4 + ks * 2 + kb) * 256 + lm * 8;
        const f16x8 bh = *(const f16x8*)&sb[co];
        acc[0][ntl] = MFMA32(ar[0][ks], bh, acc[0][ntl]);
        acc[1][ntl] = MFMA32(ar[1][ks], bh, acc[1][ntl]);
      }
  };
  auto computeP = [&](const _Float16* sb, const f16x8 ar[2][2][2]) {
    computeHalf(sb, ar[0]);
    computeHalf(sb + 4096, ar[1]);
  };

  stageB2(0, 0);
  loadA2(0, arE);
  for (int pp = 0; pp < 8; ++pp) {
    const int p = 2 * pp;
    __syncthreads();  // stage(p) + A(p) landed
    stageB2(p + 1, 1);
    loadA2(p + 1, arO);
    computeP(sB[0], arE);
    __syncthreads();
    if (p + 2 < 16) {
      stageB2(p + 2, 0);
      loadA2(p + 2, arE);
    }
    computeP(sB[1], arO);
  }
  // epilogue: C/D layout col=lane&31, row=(q&3)+8*(q>>2)+4*kb ; C[((il*128+c)*36+r)*32+w]
#pragma unroll
  for (int mt = 0; mt < 2; ++mt)
#pragma unroll
    for (int ntl = 0; ntl < 2; ++ntl) {
      const int cc = n0b + nb0 + ntl;
      const f32x16 a = acc[mt][ntl];
#pragma unroll
      for (int q = 0; q < 16; ++q) {
        const int row32 = (q & 3) + 8 * (q >> 2) + 4 * kb;
        const int m = (Mt0 + mt) * 32 + row32;
        const int il = m / NR, r = m - il * NR;
        C[((size_t)il * 128 + cc) * (NR * NW) + r * NW + lm] = a[q];
      }
    }
}

// ============ fused v12 = v11 body + slab-summed gram staging + inline norms ==============
#define GCP 1040
__global__ __launch_bounds__(192, 4) void fused_attn_kernel(
    const float* __restrict__ C, const float* __restrict__ Gimg, const float* __restrict__ Gcap,
    float* __restrict__ out) {
  const int i = blockIdx.x;
  const int cg = blockIdx.y;  // 0..63, 2 caps per block
  const int tid = threadIdx.x;
  const int wv = tid >> 6, lane = tid & 63;
  __shared__ float sS[2][NR * 36];   // scores, row stride 36
  __shared__ float sGi[NR * NR];     // image gram 36x36 (summed over 4 slabs)
  __shared__ float sGc[2 * GCP];     // caption grams 32x32, padded stride 1040
  __shared__ float sInvR[2][NR];
  __shared__ float sInvC[2][NW];
  __shared__ float sVal[72];
  __shared__ float red[2];
  if (tid < 2) red[tid] = 0.f;
  // ---- stage scores + grams (sum 4 k-slabs) ----
  const float* Cp = C + ((size_t)i * 128 + cg * 2) * (NR * NW);
  for (int t = tid; t < 2 * 288; t += 192) {
    const int cap = t / 288, rem = t - cap * 288;
    const int r = rem >> 3, wq = rem & 7;
    const float4 v = *(const float4*)(Cp + cap * (NR * NW) + r * NW + wq * 4);
    *(float4*)&sS[cap][r * 36 + wq * 4] = v;
  }
  const float* Gi = Gimg + (size_t)i * (NR * NR);
  for (int t = tid; t < 324; t += 192) {
    const float4 g0 = *(const float4*)(Gi + t * 4);
    const float4 g1 = *(const float4*)(Gi + GI_SLAB + t * 4);
    const float4 g2 = *(const float4*)(Gi + 2 * GI_SLAB + t * 4);
    const float4 g3 = *(const float4*)(Gi + 3 * GI_SLAB + t * 4);
    float4 s;
    s.x = (g0.x + g1.x) + (g2.x + g3.x);
    s.y = (g0.y + g1.y) + (g2.y + g3.y);
    s.z = (g0.z + g1.z) + (g2.z + g3.z);
    s.w = (g0.w + g1.w) + (g2.w + g3.w);
    *(float4*)&sGi[t * 4] = s;
  }
  const float* Gc0 = Gcap + (size_t)(cg * 2) * (NW * NW);
  for (int t = tid; t < 512; t += 192) {
    const int cap = t >> 8, q = t & 255;
    const float4 g0 = *(const float4*)(Gc0 + cap * (NW * NW) + q * 4);
    const float4 g1 = *(const float4*)(Gc0 + GC_SLAB + cap * (NW * NW) + q * 4);
    const float4 g2 = *(const float4*)(Gc0 + 2 * GC_SLAB + cap * (NW * NW) + q * 4);
    const float4 g3 = *(const float4*)(Gc0 + 3 * GC_SLAB + cap * (NW * NW) + q * 4);
    float4 s;
    s.x = (g0.x + g1.x) + (g2.x + g3.x);
    s.y = (g0.y + g1.y) + (g2.y + g3.y);
    s.z = (g0.z + g1.z) + (g2.z + g3.z);
    s.w = (g0.w + g1.w) + (g2.w + g3.w);
    *(float4*)&sGc[cap * GCP + q * 4] = s;
  }
  __syncthreads();
  // ---- norm phase: col-norms (tid<64) + row-norms (tid 64..135) ----
  if (tid < 64) {
    const int cap = tid >> 5, w = tid & 31;
    float c0 = 0.f, c1 = 0.f, c2 = 0.f, c3 = 0.f;
#pragma unroll
    for (int j = 0; j < NR; j += 4) {
      const float l0 = leakyf(sS[cap][(j + 0) * 36 + w]);
      const float l1 = leakyf(sS[cap][(j + 1) * 36 + w]);
      const float l2 = leakyf(sS[cap][(j + 2) * 36 + w]);
      const float l3 = leakyf(sS[cap][(j + 3) * 36 + w]);
      c0 = fmaf(l0, l0, c0); c1 = fmaf(l1, l1, c1);
      c2 = fmaf(l2, l2, c2); c3 = fmaf(l3, l3, c3);
    }
    sInvC[cap][w] = 20.f / (sqrtf((c0 + c1) + (c2 + c3)) + EPSF);
  } else if (tid < 136) {
    const int u = tid - 64;
    const int cap = u / NR, r = u - cap * NR;
    float r0 = 0.f, r1 = 0.f, r2 = 0.f, r3 = 0.f;
#pragma unroll
    for (int k = 0; k < 8; ++k) {
      const float4 v = *(const float4*)&sS[cap][r * 36 + k * 4];
      float l;
      l = leakyf(v.x); r0 = fmaf(l, l, r0);
      l = leakyf(v.y); r1 = fmaf(l, l, r1);
      l = leakyf(v.z); r2 = fmaf(l, l, r2);
      l = leakyf(v.w); r3 = fmaf(l, l, r3);
    }
    sInvR[cap][r] = 20.f / (sqrtf((r0 + r1) + (r2 + r3)) + EPSF);
  }
  __syncthreads();
  // ---- main phase: wave 0 t2i (2 caps x 32 w); waves 1-2 i2t (36 units each) ----
  if (tid < 64) {
    const int cap = tid >> 5, w = tid & 31;
    float z[NR];
    float m0 = -1e30f, m1 = -1e30f, m2 = -1e30f, m3 = -1e30f;
#pragma unroll
    for (int j = 0; j < NR; j += 4) {
      z[j + 0] = leakyf(sS[cap][(j + 0) * 36 + w]) * sInvR[cap][j + 0]; m0 = fmaxf(m0, z[j + 0]);
      z[j + 1] = leakyf(sS[cap][(j + 1) * 36 + w]) * sInvR[cap][j + 1]; m1 = fmaxf(m1, z[j + 1]);
      z[j + 2] = leakyf(sS[cap][(j + 2) * 36 + w]) * sInvR[cap][j + 2]; m2 = fmaxf(m2, z[j + 2]);
      z[j + 3] = leakyf(sS[cap][(j + 3) * 36 + w]) * sInvR[cap][j + 3]; m3 = fmaxf(m3, z[j + 3]);
    }
    const float mz = fmaxf(fmaxf(m0, m1), fmaxf(m2, m3));
    float a0 = 0.f, a1 = 0.f, a2 = 0.f, a3 = 0.f;
#pragma unroll
    for (int j = 0; j < NR; j += 4) {
      z[j + 0] = __expf(z[j + 0] - mz); a0 += z[j + 0];
      z[j + 1] = __expf(z[j + 1] - mz); a1 += z[j + 1];
      z[j + 2] = __expf(z[j + 2] - mz); a2 += z[j + 2];
      z[j + 3] = __expf(z[j + 3] - mz); a3 += z[j + 3];
    }
    const float thr = ((a0 + a1) + (a2 + a3)) * (1.f / NR);
    float n0 = 0.f, n1 = 0.f, n2 = 0.f, n3 = 0.f;
#pragma unroll
    for (int j = 0; j < NR; j += 4) {
      z[j + 0] = (z[j + 0] > thr) ? z[j + 0] : 0.f;
      n0 = fmaf(z[j + 0], sS[cap][(j + 0) * 36 + w], n0);
      z[j + 1] = (z[j + 1] > thr) ? z[j + 1] : 0.f;
      n1 = fmaf(z[j + 1], sS[cap][(j + 1) * 36 + w], n1);
      z[j + 2] = (z[j + 2] > thr) ? z[j + 2] : 0.f;
      n2 = fmaf(z[j + 2], sS[cap][(j + 2) * 36 + w], n2);
      z[j + 3] = (z[j + 3] > thr) ? z[j + 3] : 0.f;
      n3 = fmaf(z[j + 3], sS[cap][(j + 3) * 36 + w], n3);
    }
    const float num = (n0 + n1) + (n2 + n3);
    // triangular QF, 4-way accumulators
    float d0 = 0.f, d1 = 0.f, d2 = 0.f, d3 = 0.f;
#pragma unroll
    for (int j = 0; j < NR; ++j) {
      const int cj = j >> 2;
      float h0, h1, h2, h3;
      {
        const float4 g = *(const float4*)&sGi[j * 36 + cj * 4];
        const float ge[4] = {g.x, g.y, g.z, g.w};
        h0 = 0.5f * ge[j & 3] * z[j];
        h1 = 0.f; h2 = 0.f; h3 = 0.f;
#pragma unroll
        for (int e = 0; e < 4; ++e) {
          const int k = cj * 4 + e;
          if (k > j) h1 = fmaf(ge[e], z[k], h1);
        }
      }
#pragma unroll
      for (int c = 0; c < 9; ++c) {
        if (c > cj) {
          const float4 g = *(const float4*)&sGi[j * 36 + c * 4];
          h0 = fmaf(g.x, z[c * 4 + 0], h0);
          h1 = fmaf(g.y, z[c * 4 + 1], h1);
          h2 = fmaf(g.z, z[c * 4 + 2], h2);
          h3 = fmaf(g.w, z[c * 4 + 3], h3);
        }
      }
      const float h = (h0 + h1) + (h2 + h3);
      if ((j & 3) == 0) d0 = fmaf(z[j], h, d0);
      else if ((j & 3) == 1) d1 = fmaf(z[j], h, d1);
      else if ((j & 3) == 2) d2 = fmaf(z[j], h, d2);
      else d3 = fmaf(z[j], h, d3);
    }
    const float den2 = (d0 + d1) + (d2 + d3);
    const float cn = fmaxf(sqrtf(sGc[cap * GCP + w * 33]), EPSF);  // diag w*32+w
    const float val = num / (cn * sqrtf(2.f * den2) + 1e-30f);
    float contrib = val * (1.f / NW);
#pragma unroll
    for (int d = 1; d < 32; d <<= 1) contrib += __shfl_xor(contrib, d, 64);
    if ((tid & 31) == 0) atomicAdd(&red[cap], contrib);
  } else if (lane < 36) {
    const int u = (wv - 1) * 36 + lane;   // waves 1-2, 36 units each: u 0..71
    const int cap = u / NR, r = u - cap * NR;
    float z[NW];
    float m0 = -1e30f, m1 = -1e30f, m2 = -1e30f, m3 = -1e30f;
#pragma unroll
    for (int k = 0; k < 8; ++k) {
      const float4 v = *(const float4*)&sS[cap][r * 36 + k * 4];
      z[k * 4 + 0] = leakyf(v.x) * sInvC[cap][k * 4 + 0]; m0 = fmaxf(m0, z[k * 4 + 0]);
      z[k * 4 + 1] = leakyf(v.y) * sInvC[cap][k * 4 + 1]; m1 = fmaxf(m1, z[k * 4 + 1]);
      z[k * 4 + 2] = leakyf(v.z) * sInvC[cap][k * 4 + 2]; m2 = fmaxf(m2, z[k * 4 + 2]);
      z[k * 4 + 3] = leakyf(v.w) * sInvC[cap][k * 4 + 3]; m3 = fmaxf(m3, z[k * 4 + 3]);
    }
    const float mz = fmaxf(fmaxf(m0, m1), fmaxf(m2, m3));
    float a0 = 0.f, a1 = 0.f, a2 = 0.f, a3 = 0.f;
#pragma unroll
    for (int w = 0; w < NW; w += 4) {
      z[w + 0] = __expf(z[w + 0] - mz); a0 += z[w + 0];
      z[w + 1] = __expf(z[w + 1] - mz); a1 += z[w + 1];
      z[w + 2] = __expf(z[w + 2] - mz); a2 += z[w + 2];
      z[w + 3] = __expf(z[w + 3] - mz); a3 += z[w + 3];
    }
    const float thr = ((a0 + a1) + (a2 + a3)) * (1.f / NW);
    float n0 = 0.f, n1 = 0.f, n2 = 0.f, n3 = 0.f;
#pragma unroll
    for (int k = 0; k < 8; ++k) {
      const float4 v = *(const float4*)&sS[cap][r * 36 + k * 4];
      z[k * 4 + 0] = (z[k * 4 + 0] > thr) ? z[k * 4 + 0] : 0.f;
      n0 = fmaf(z[k * 4 + 0], v.x, n0);
      z[k * 4 + 1] = (z[k * 4 + 1] > thr) ? z[k * 4 + 1] : 0.f;
      n1 = fmaf(z[k * 4 + 1], v.y, n1);
      z[k * 4 + 2] = (z[k * 4 + 2] > thr) ? z[k * 4 + 2] : 0.f;
      n2 = fmaf(z[k * 4 + 2], v.z, n2);
      z[k * 4 + 3] = (z[k * 4 + 3] > thr) ? z[k * 4 + 3] : 0.f;
      n3 = fmaf(z[k * 4 + 3], v.w, n3);
    }
    const float num = (n0 + n1) + (n2 + n3);
    const float* Gp = &sGc[cap * GCP];
    float d0 = 0.f, d1 = 0.f, d2 = 0.f, d3 = 0.f;
#pragma unroll
    for (int w = 0; w < NW; ++w) {
      const int cw = w >> 2;
      float h0, h1, h2, h3;
      {
        const float4 g = *(const float4*)&Gp[w * 32 + cw * 4];
        const float ge[4] = {g.x, g.y, g.z, g.w};
        h0 = 0.5f * ge[w & 3] * z[w];
        h1 = 0.f; h2 = 0.f; h3 = 0.f;
#pragma unroll
        for (int e = 0; e < 4; ++e) {
          const int k = cw * 4 + e;
          if (k > w) h1 = fmaf(ge[e], z[k], h1);
        }
      }
#pragma unroll
      for (int c = 0; c < 8; ++c) {
        if (c > cw) {
          const float4 g = *(const float4*)&Gp[w * 32 + c * 4];
          h0 = fmaf(g.x, z[c * 4 + 0], h0);
          h1 = fmaf(g.y, z[c * 4 + 1], h1);
          h2 = fmaf(g.z, z[c * 4 + 2], h2);
          h3 = fmaf(g.w, z[c * 4 + 3], h3);
        }
      }
      const float h = (h0 + h1) + (h2 + h3);
      if ((w & 3) == 0) d0 = fmaf(z[w], h, d0);
      else if ((w & 3) == 1) d1 = fmaf(z[w], h, d1);
      else if ((w & 3) == 2) d2 = fmaf(z[w], h, d2);
      else d3 = fmaf(z[w], h, d3);
    }
    const float den2 = (d0 + d1) + (d2 + d3);
    const float rn = fmaxf(sqrtf(sGi[r * 37]), EPSF);  // diag r*36+r
    const float val = num / (rn * sqrtf(2.f * den2) + 1e-30f);
    sVal[u] = val * (1.f / NR);
  }
  __syncthreads();
  // ---- i2t reduction: 2 caps x 32 lanes sum the 36 per-r values ----
  if (tid < 64) {
    const int cap = tid >> 5, x = tid & 31;
    float v = sVal[cap * 36 + x];
    if (x < 4) v += sVal[cap * 36 + 32 + x];
#pragma unroll
    for (int d = 1; d < 32; d <<= 1) v += __shfl_xor(v, d, 64);
    if ((tid & 31) == 0) atomicAdd(&red[cap], v);
  }
  __syncthreads();
  if (tid < 2) out[(size_t)i * 128 + cg * 2 + tid] = red[tid];
}

extern "C" void kernel_launch(void* const* d_in, const int* in_sizes, int n_in,
                              void* d_out, int out_size, void* d_ws, size_t ws_size,
                              hipStream_t stream) {
  (void)in_sizes; (void)n_in; (void)out_size; (void)ws_size;
  const float* images = (const float*)d_in[0];
  const float* captions = (const float*)d_in[1];
  float* out = (float*)d_out;

  char* wb = (char*)d_ws;
  _Float16* Ahf = (_Float16*)wb; wb += (size_t)4608 * 1024 * 2;
  _Float16* Bhf = (_Float16*)wb; wb += (size_t)4096 * 1024 * 2;
  float* Gimg = (float*)wb; wb += (size_t)4 * GI_SLAB * 4;
  float* Gcap = (float*)wb; wb += (size_t)4 * GC_SLAB * 4;
  float* C = (float*)wb;

  prep_kernel<<<1024, 256, 0, stream>>>(images, captions, Gimg, Gcap, Ahf, Bhf);
  mfma_gemm_kernel<<<1152, 256, 0, stream>>>(Ahf, Bhf, C);
  fused_attn_kernel<<<dim3(128, 64), 192, 0, stream>>>(C, Gimg, Gcap, out);
}